// Round 17
// baseline (227.099 us; speedup 1.0000x reference)
//
#include <hip/hip_runtime.h>

#define TOKENS 8192
#define IN_F   4096
#define OUT_F  4096

#define BM 256
#define BN 256
#define BK 64
#define NT (IN_F / BK)   // 64 K-tiles

typedef __attribute__((ext_vector_type(4))) float  f32x4;
typedef __attribute__((ext_vector_type(4))) int    i32x4;

typedef const __attribute__((address_space(1))) void gas_void;
typedef __attribute__((address_space(3))) void las_void;

// ---------------------------------------------------------------------------
// quant_x: per-token symmetric i8 quantization (r6-verified).
// ---------------------------------------------------------------------------
__global__ __launch_bounds__(256) void quant_x_kernel(const float* __restrict__ x,
                                                      signed char* __restrict__ xq,
                                                      float* __restrict__ dx) {
    const int row  = blockIdx.x;
    const int tid  = threadIdx.x;
    const int lane = tid & 63;
    const int wv   = tid >> 6;
    const float* xr = x + (size_t)row * IN_F;

    float v[16];
#pragma unroll
    for (int k = 0; k < 4; ++k) {
        f32x4 t = *(const f32x4*)(xr + k * 1024 + tid * 4);
#pragma unroll
        for (int j = 0; j < 4; ++j) v[k * 4 + j] = t[j];
    }
    float m = 0.f;
#pragma unroll
    for (int j = 0; j < 16; ++j) m = fmaxf(m, fabsf(v[j]));
#pragma unroll
    for (int off = 32; off >= 1; off >>= 1) m = fmaxf(m, __shfl_xor(m, off));
    __shared__ float sm[4];
    if (lane == 0) sm[wv] = m;
    __syncthreads();
    m = fmaxf(fmaxf(sm[0], sm[1]), fmaxf(sm[2], sm[3]));

    const float inv = 127.0f / m;
    if (tid == 0) dx[row] = m * (1.0f / 127.0f);

    int* out = (int*)(xq + (size_t)row * IN_F);
#pragma unroll
    for (int k = 0; k < 4; ++k) {
        int p = 0;
#pragma unroll
        for (int j = 0; j < 4; ++j) {
            int q = (int)rintf(v[k * 4 + j] * inv);
            p |= (q & 0xff) << (8 * j);
        }
        out[k * 256 + tid] = p;
    }
}

// ---------------------------------------------------------------------------
// quant_w: per-out-row integer re-scale of ternary weights (r6-verified).
// ---------------------------------------------------------------------------
__global__ __launch_bounds__(256) void quant_w_kernel(const int* __restrict__ tern,
                                                      const float* __restrict__ scales,
                                                      signed char* __restrict__ wq,
                                                      float* __restrict__ dw) {
    const int o   = blockIdx.x;
    const int tid = threadIdx.x;
    const float* sr = scales + o * 32;

    float smax = 0.f;
#pragma unroll
    for (int g = 0; g < 32; ++g) smax = fmaxf(smax, sr[g]);
    if (tid == 0) dw[o] = smax * (1.0f / 127.0f);

    const int g  = tid >> 3;
    const int iq = (int)rintf(sr[g] * (127.0f / smax));

    const i32x4* tp = (const i32x4*)(tern + (size_t)o * IN_F + tid * 16);
    i32x4 out;
#pragma unroll
    for (int k = 0; k < 4; ++k) {
        i32x4 t = tp[k];
        int p = 0;
#pragma unroll
        for (int j = 0; j < 4; ++j) p |= ((t[j] * iq) & 0xff) << (8 * j);
        out[k] = p;
    }
    *(i32x4*)(wq + (size_t)o * IN_F + tid * 16) = out;
}

// ---------------------------------------------------------------------------
// C = (xq . wq^T) * dx[m] * dw[n],  i8 MFMA 16x16x64, i32 acc.
// r17: BARRIER-FREE flag-synchronized K-loop (producer-consumer, symmetric).
// 256x256 tile, BK=64, 8 waves (2M x 4N), per-wave 128x64, acc 128 AGPR.
// LDS: As[4][16KB] + Bs[4][16KB] = 128 KiB (4-deep) + 8 flag words.
// Each wave stages 1/8 of every tile (waves 0-3: A quarter w; 4-7: B quarter
// w-4; 4 x global_load_lds of 1KB each), 2 tiles ahead. Sync via monotone
// LDS counters (no resets -> no ABA):
//   stagedCnt[b]: +1 per wave when its loads for b's current occupant landed
//                 (gated by counted vmcnt BEFORE the flag -> flag => data).
//   doneCnt[b]:   +1 per wave after its 12 ds_reads of b's occupant.
// Wave body, tile t (b = t&3):
//   1. spin stagedCnt[b] >= 8*(t/4)+8            [occupant t fully staged]
//   2. 12 ds_read + 4 QUADs (compiler interleaves; no gates)
//   3. sched_barrier; lane0: doneCnt[b] += 1     [reads issued, DS in-order]
//   4. s = t+2: spin doneCnt[s&3] >= 8*(s/4)     [old occupant s-4 consumed]
//   5. stage s into buf s&3 (4 gloads); vmcnt(4) [drains t+1's own loads];
//      lane0: stagedCnt[(t+1)&3] += 1
// No s_barrier in the loop: waves de-phase, so one wave's LDS read burst
// services under another's MFMA burst (the overlap every barriered schedule
// failed to produce, r2-r15). Deadlock-free: step-4 spin depends only on
// tiles <= t-2; step-1 on all waves' step-5 at t-1 (inductive).
// sched_barrier(0) after each spin/before each flag: stops compiler
// hoisting non-faulting ds_reads across control deps (rule 18 class).
// ---------------------------------------------------------------------------

#define QUAD(MI0, NI0)                                                         \
  do {                                                                         \
    __builtin_amdgcn_s_setprio(1);                                             \
    _Pragma("unroll") for (int mi = 0; mi < 4; ++mi)                           \
      _Pragma("unroll") for (int ni = 0; ni < 2; ++ni)                         \
          acc[(MI0)+mi][(NI0)+ni] = __builtin_amdgcn_mfma_i32_16x16x64_i8(     \
              a[(MI0)+mi], bf[(NI0)+ni], acc[(MI0)+mi][(NI0)+ni], 0, 0, 0);    \
    __builtin_amdgcn_s_setprio(0);                                             \
  } while (0)

#define SPIN_GE(IDX, TGT)                                                      \
  do {                                                                         \
    while (*(volatile int*)&flg[IDX] < (TGT)) __builtin_amdgcn_s_sleep(2);     \
    __builtin_amdgcn_sched_barrier(0);                                         \
  } while (0)

__global__ __launch_bounds__(512, 2) void gemm_i8_kernel(
        const signed char* __restrict__ A,
        const signed char* __restrict__ B,
        const float* __restrict__ dX,
        const float* __restrict__ dW,
        float* __restrict__ C) {
    __shared__ __align__(16) signed char As[4 * 16384];
    __shared__ __align__(16) signed char Bs[4 * 16384];
    __shared__ int flg[8];   // [0..3] stagedCnt, [4..7] doneCnt

    const int tid  = threadIdx.x;
    const int wave = tid >> 6;
    const int lane = tid & 63;
    const int wm   = wave >> 2;        // 0-1
    const int wn   = wave & 3;         // 0-3
    const int lg   = lane >> 4;        // 0-3
    const int lr   = lane & 15;        // 0-15

    int bid = blockIdx.x;
    bid = (bid & 7) * (512 >> 3) + (bid >> 3);   // XCD swizzle, 512%8==0
    const int bm = bid >> 4;           // 0-31
    const int bn = bid & 15;           // 0-15

    const size_t a_row0 = (size_t)bm * BM;
    const size_t b_row0 = (size_t)bn * BN;

    if (tid < 8) flg[tid] = 0;
    __syncthreads();                   // only barrier in the kernel

    // ---- per-wave staging map: 4 gload ops, op i -> global j = wave*4+i.
    // j<16: A (h=(j>>3)&1, sub j&7); j>=16: B. unit = 8KB = 128 rows x 64B,
    // r8-verified swizzle; phys u16 = (j&7)*1024 + lane*16, u=(j&7)*64+lane.
    const bool wavA = (wave < 4);
    const signed char* gbase[4];
    int dstoff[4];
#pragma unroll
    for (int i = 0; i < 4; ++i) {
        const int j  = wave * 4 + i;
        const int u  = (j & 7) * 64 + lane;
        const int sx = (u & 7) ^ ((u >> 3) & 7);
        const int srow = ((u >> 3) << 1) | ((sx >> 2) & 1);
        const int scol = (sx & 3) << 4;
        const size_t grow = (wavA ? a_row0 : b_row0) + (size_t)(((j >> 3) & 1) * 128 + srow);
        gbase[i]  = (wavA ? A : B) + grow * IN_F + scol;
        dstoff[i] = ((j >> 3) & 1) * 8192 + (j & 7) * 1024 + lane * 16;
    }
    signed char* Ldst = wavA ? As : Bs;

    auto stage = [&](int buf, int k0) {
#pragma unroll
        for (int i = 0; i < 4; ++i)
            __builtin_amdgcn_global_load_lds((gas_void*)(gbase[i] + k0),
                                             (las_void*)(Ldst + buf * 16384 + dstoff[i]),
                                             16, 0, 0);
    };

    i32x4 acc[8][4] = {};
    i32x4 a[8], bf[4];

    auto physoff = [&](int r, int c0) {
        return ((r >> 1) << 7) + (((((r & 1) << 6) | c0) ^ (((r >> 1) & 7) << 4)));
    };
    int pA[8], pB[4];
#pragma unroll
    for (int mi = 0; mi < 8; ++mi) pA[mi] = physoff(wm * 128 + mi * 16 + lr, lg << 4);
#pragma unroll
    for (int ni = 0; ni < 4; ++ni) pB[ni] = physoff(wn * 64 + ni * 16 + lr, lg << 4);

    // ---- prologue: stage tiles 0,1; flag tile 0 (tile 1 flagged in body 0)
    stage(0, 0);
    stage(1, BK);
    asm volatile("s_waitcnt vmcnt(4)" ::: "memory");
    __builtin_amdgcn_sched_barrier(0);
    if (lane == 0) atomicAdd(&flg[0], 1);

    for (int t = 0; t < NT; ++t) {
        const int b = t & 3;

        // 1. occupant t fully staged by all 8 waves
        SPIN_GE(b, 8 * (t >> 2) + 8);

        // 2. reads + MFMAs (single region; compiler-scheduled lgkm)
#pragma unroll
        for (int mi = 0; mi < 8; ++mi) a[mi] = *(const i32x4*)&As[b * 16384 + pA[mi]];
#pragma unroll
        for (int ni = 0; ni < 4; ++ni) bf[ni] = *(const i32x4*)&Bs[b * 16384 + pB[ni]];
        QUAD(0, 0); QUAD(0, 2); QUAD(4, 0); QUAD(4, 2);

        // 3. mark consumed (DS in-order after the reads; fence vs hoisting)
        __builtin_amdgcn_sched_barrier(0);
        if (lane == 0) atomicAdd(&flg[4 + b], 1);

        // 4-5. stage tile t+2; flag tile t+1 after own-loads drain
        if (t + 2 < NT) {
            const int s = t + 2, bs = s & 3;
            SPIN_GE(4 + bs, 8 * (s >> 2));
            stage(bs, s * BK);
            asm volatile("s_waitcnt vmcnt(4)" ::: "memory");
            __builtin_amdgcn_sched_barrier(0);
            if (lane == 0) atomicAdd(&flg[(t + 1) & 3], 1);
        } else if (t + 1 < NT) {
            asm volatile("s_waitcnt vmcnt(0)" ::: "memory");
            __builtin_amdgcn_sched_barrier(0);
            if (lane == 0) atomicAdd(&flg[(t + 1) & 3], 1);
        }
    }

    // ---- epilogue: out = acc * dx[row] * dw[col]; C/D col=lane&15, row=lg*4+j
    float dwc[4];
#pragma unroll
    for (int ni = 0; ni < 4; ++ni) dwc[ni] = dW[b_row0 + wn * 64 + ni * 16 + lr];

    float* Cp = C + (a_row0 + wm * 128) * (size_t)OUT_F + b_row0 + wn * 64;
#pragma unroll
    for (int mi = 0; mi < 8; ++mi) {
#pragma unroll
        for (int j = 0; j < 4; ++j) {
            const int r = mi * 16 + lg * 4 + j;
            const float dxr = dX[a_row0 + wm * 128 + r];
#pragma unroll
            for (int ni = 0; ni < 4; ++ni)
                Cp[(size_t)r * OUT_F + ni * 16 + lr] =
                    (float)acc[mi][ni][j] * dxr * dwc[ni];
        }
    }
}

extern "C" void kernel_launch(void* const* d_in, const int* in_sizes, int n_in,
                              void* d_out, int out_size, void* d_ws, size_t ws_size,
                              hipStream_t stream) {
    const float* x      = (const float*)d_in[0];
    const int*   tern   = (const int*)d_in[1];
    const float* scales = (const float*)d_in[2];

    signed char* xq = (signed char*)d_ws;
    signed char* wq = xq + (size_t)TOKENS * IN_F;
    float*       dx = (float*)(wq + (size_t)OUT_F * IN_F);
    float*       dw = dx + TOKENS;

    quant_x_kernel<<<TOKENS, 256, 0, stream>>>(x, xq, dx);
    quant_w_kernel<<<OUT_F, 256, 0, stream>>>(tern, scales, wq, dw);

    dim3 grid((TOKENS / BM) * (OUT_F / BN));   // 512
    gemm_i8_kernel<<<grid, 512, 0, stream>>>(xq, wq, dx, dw, (float*)d_out);
}

// Round 18
// 177.272 us; speedup vs baseline: 1.2811x; 1.2811x over previous
//
#include <hip/hip_runtime.h>

#define TOKENS 8192
#define IN_F   4096
#define OUT_F  4096

#define BM 256
#define BN 256
#define BK 128
#define NT (IN_F / BK)   // 32 K-tiles

typedef __attribute__((ext_vector_type(4))) float  f32x4;
typedef __attribute__((ext_vector_type(4))) int    i32x4;

typedef const __attribute__((address_space(1))) void gas_void;
typedef __attribute__((address_space(3))) void las_void;

// ---------------------------------------------------------------------------
// quant_x: per-token symmetric i8 quantization. One block (256 thr) per row.
// xq[r][i] = rint(x*127/amax_r), dx[r] = amax_r/127.
// ---------------------------------------------------------------------------
__global__ __launch_bounds__(256) void quant_x_kernel(const float* __restrict__ x,
                                                      signed char* __restrict__ xq,
                                                      float* __restrict__ dx) {
    const int row  = blockIdx.x;
    const int tid  = threadIdx.x;
    const int lane = tid & 63;
    const int wv   = tid >> 6;
    const float* xr = x + (size_t)row * IN_F;

    float v[16];
#pragma unroll
    for (int k = 0; k < 4; ++k) {
        f32x4 t = *(const f32x4*)(xr + k * 1024 + tid * 4);
#pragma unroll
        for (int j = 0; j < 4; ++j) v[k * 4 + j] = t[j];
    }
    float m = 0.f;
#pragma unroll
    for (int j = 0; j < 16; ++j) m = fmaxf(m, fabsf(v[j]));
#pragma unroll
    for (int off = 32; off >= 1; off >>= 1) m = fmaxf(m, __shfl_xor(m, off));
    __shared__ float sm[4];
    if (lane == 0) sm[wv] = m;
    __syncthreads();
    m = fmaxf(fmaxf(sm[0], sm[1]), fmaxf(sm[2], sm[3]));

    const float inv = 127.0f / m;
    if (tid == 0) dx[row] = m * (1.0f / 127.0f);

    int* out = (int*)(xq + (size_t)row * IN_F);
#pragma unroll
    for (int k = 0; k < 4; ++k) {
        int p = 0;
#pragma unroll
        for (int j = 0; j < 4; ++j) {
            int q = (int)rintf(v[k * 4 + j] * inv);
            p |= (q & 0xff) << (8 * j);
        }
        out[k * 256 + tid] = p;
    }
}

// ---------------------------------------------------------------------------
// quant_w: per-out-row integer re-scale of ternary weights.
// s_max = max_g scales[o*32+g]; q_g = rint(s_g*127/s_max); wq = tern*q_g;
// dw[o] = s_max/127.  One block per out-row; thread t -> 16 elems, group t/8.
// ---------------------------------------------------------------------------
__global__ __launch_bounds__(256) void quant_w_kernel(const int* __restrict__ tern,
                                                      const float* __restrict__ scales,
                                                      signed char* __restrict__ wq,
                                                      float* __restrict__ dw) {
    const int o   = blockIdx.x;
    const int tid = threadIdx.x;
    const float* sr = scales + o * 32;

    float smax = 0.f;
#pragma unroll
    for (int g = 0; g < 32; ++g) smax = fmaxf(smax, sr[g]);
    if (tid == 0) dw[o] = smax * (1.0f / 127.0f);

    const int g  = tid >> 3;
    const int iq = (int)rintf(sr[g] * (127.0f / smax));

    const i32x4* tp = (const i32x4*)(tern + (size_t)o * IN_F + tid * 16);
    i32x4 out;
#pragma unroll
    for (int k = 0; k < 4; ++k) {
        i32x4 t = tp[k];
        int p = 0;
#pragma unroll
        for (int j = 0; j < 4; ++j) p |= ((t[j] * iq) & 0xff) << (8 * j);
        out[k] = p;
    }
    *(i32x4*)(wq + (size_t)o * IN_F + tid * 16) = out;
}

// ---------------------------------------------------------------------------
// C[M][N] = (xq . wq^T) * dx[m] * dw[n],  i8 MFMA 16x16x64, i32 acc.
// 256x256 tile, BK=128, 8 waves (2M x 4N), per-wave 128x64.
// BEST MEASURED CONFIGURATION (r6: 137.8us GEMM / 177.8us total; r16
// reproduction: 139us / 178.0us). Two-barrier schedule (r5-verified),
// counted vmcnt(4), T2 both-sides swizzle (0 bank conflicts), T5 setprio,
// XCD-aware block swizzle. LDS: [2][256][128] i8 x2 = 128 KiB.
// Swizzle involution: LDS(row,col) = G(row, col ^ ((row&7)<<4)).
// Session ledger: 11 structural alternatives (phase splits, read-ahead,
// triple-buffer single-region, 2-blocks/CU, B-direct x4, pure-register,
// barrier-free flags) all land at >= this config; per-tile cycles match
// MFMA(1306cy) + LDS-service(~1250cy) serialized — breaking that requires
// asm-level K-loop scheduling beyond HIP source control.
// ---------------------------------------------------------------------------

#define QUAD(MI0, NI0)                                                         \
  do {                                                                         \
    __builtin_amdgcn_s_setprio(1);                                             \
    _Pragma("unroll") for (int mi = 0; mi < 4; ++mi)                           \
      _Pragma("unroll") for (int ni = 0; ni < 2; ++ni)                         \
        _Pragma("unroll") for (int kk = 0; kk < 2; ++kk)                       \
          acc[(MI0)+mi][(NI0)+ni] = __builtin_amdgcn_mfma_i32_16x16x64_i8(     \
              a[(MI0)+mi][kk], b[(NI0)+ni][kk], acc[(MI0)+mi][(NI0)+ni],0,0,0);\
    __builtin_amdgcn_s_setprio(0);                                             \
  } while (0)

__global__ __launch_bounds__(512, 2) void gemm_i8_kernel(
        const signed char* __restrict__ A,
        const signed char* __restrict__ B,
        const float* __restrict__ dX,
        const float* __restrict__ dW,
        float* __restrict__ C) {
    __shared__ __align__(16) signed char As[2 * 256 * 128];
    __shared__ __align__(16) signed char Bs[2 * 256 * 128];

    const int tid  = threadIdx.x;
    const int wave = tid >> 6;
    const int lane = tid & 63;
    const int wm   = wave >> 2;        // 0-1
    const int wn   = wave & 3;         // 0-3
    const int lg   = lane >> 4;        // 0-3
    const int lr   = lane & 15;        // 0-15

    int bid = blockIdx.x;
    bid = (bid & 7) * (512 >> 3) + (bid >> 3);   // XCD swizzle, 512%8==0
    const int bm = bid >> 4;           // 0-31
    const int bn = bid & 15;           // 0-15

    const size_t a_row0 = (size_t)bm * BM;
    const size_t b_row0 = (size_t)bn * BN;

    // stage one half-tile (128 rows x 128 i8 = 16 KiB): 2 loads/thread.
    auto stage_half = [&](int buf, int half, int which, int k0) {
        const signed char* G = which ? B : A;
        const size_t grow0 = (which ? b_row0 : a_row0) + (size_t)half * 128;
        signed char* T = (which ? Bs : As) + buf * 32768 + half * 16384;
#pragma unroll
        for (int i = 0; i < 2; ++i) {
            const int qe    = (i * 512 + tid) * 16;         // byte offset in half
            const int row_h = qe >> 7;                      // 0..127
            const int cswz  = (qe & 127) ^ ((row_h & 7) << 4);
            const signed char* src = G + (grow0 + row_h) * IN_F + k0 + cswz;
            signed char* dst = T + i * 8192 + wave * 1024;  // wave-uniform base
            __builtin_amdgcn_global_load_lds((gas_void*)src, (las_void*)dst, 16, 0, 0);
        }
    };

    i32x4 acc[8][4] = {};
    i32x4 a[8][2], b[4][2];

    const int sw16 = (lr & 7) << 4;
    const int arow = (wm * 128 + lr) * 128;
    const int brow = (wn * 64  + lr) * 128;

    auto rdA = [&](int mi, int base) {
        a[mi][0] = *(const i32x4*)&As[base + arow + mi * 2048 + ((lg * 16) ^ sw16)];
        a[mi][1] = *(const i32x4*)&As[base + arow + mi * 2048 + ((64 + lg * 16) ^ sw16)];
    };
    auto rdB = [&](int ni, int base) {
        b[ni][0] = *(const i32x4*)&Bs[base + brow + ni * 2048 + ((lg * 16) ^ sw16)];
        b[ni][1] = *(const i32x4*)&Bs[base + brow + ni * 2048 + ((64 + lg * 16) ^ sw16)];
    };

    // ---- prologue: tile0 fully + tile1 A-halves; drain tile0, keep 4 in flight
    stage_half(0, 0, 0, 0);  stage_half(0, 1, 0, 0);
    stage_half(0, 0, 1, 0);  stage_half(0, 1, 1, 0);
    stage_half(1, 0, 0, BK); stage_half(1, 1, 0, BK);
    asm volatile("s_waitcnt vmcnt(4)" ::: "memory");
    __builtin_amdgcn_sched_barrier(0);
    __builtin_amdgcn_s_barrier();
    __builtin_amdgcn_sched_barrier(0);

    for (int t = 0; t < NT; ++t) {
        const int buf  = t & 1;
        const int base = buf * 32768;
        const int bufn = buf ^ 1;

        // ---- Region 1: all ds_reads of buf t + B-staging of t+1, QUADs 1-2.
        rdA(0, base); rdA(1, base); rdA(2, base); rdA(3, base);
        rdB(0, base); rdB(1, base);
        if (t + 1 < NT) stage_half(bufn, 0, 1, (t + 1) * BK);
        QUAD(0, 0);

        rdA(4, base); rdA(5, base); rdA(6, base); rdA(7, base);
        if (t + 1 < NT) stage_half(bufn, 1, 1, (t + 1) * BK);
        QUAD(4, 0);

        rdB(2, base); rdB(3, base);
        __builtin_amdgcn_sched_barrier(0);
        __builtin_amdgcn_s_barrier();                  // #1: As[cur] reads done
        __builtin_amdgcn_sched_barrier(0);

        // ---- Region 2: A-staging of t+2 into freed As[cur], QUADs 3-4.
        if (t + 2 < NT) stage_half(buf, 0, 0, (t + 2) * BK);
        QUAD(4, 2);
        if (t + 2 < NT) stage_half(buf, 1, 0, (t + 2) * BK);
        QUAD(0, 2);

        if (t + 2 < NT) {
            asm volatile("s_waitcnt vmcnt(4)" ::: "memory");
        } else if (t + 1 < NT) {
            asm volatile("s_waitcnt vmcnt(0)" ::: "memory");
        }
        __builtin_amdgcn_sched_barrier(0);
        __builtin_amdgcn_s_barrier();                  // #2: staged halves visible
        __builtin_amdgcn_sched_barrier(0);
    }

    // ---- epilogue: out = acc * dx[row] * dw[col]; C/D layout col=lane&15,
    // row=(lane>>4)*4+j (dtype-independent, i8-verified m121-128)
    float dwc[4];
#pragma unroll
    for (int ni = 0; ni < 4; ++ni) dwc[ni] = dW[b_row0 + wn * 64 + ni * 16 + lr];

    float* Cp = C + (a_row0 + wm * 128) * (size_t)OUT_F + b_row0 + wn * 64;
#pragma unroll
    for (int mi = 0; mi < 8; ++mi) {
#pragma unroll
        for (int j = 0; j < 4; ++j) {
            const int r = mi * 16 + lg * 4 + j;
            const float dxr = dX[a_row0 + wm * 128 + r];
#pragma unroll
            for (int ni = 0; ni < 4; ++ni)
                Cp[(size_t)r * OUT_F + ni * 16 + lr] =
                    (float)acc[mi][ni][j] * dxr * dwc[ni];
        }
    }
}

extern "C" void kernel_launch(void* const* d_in, const int* in_sizes, int n_in,
                              void* d_out, int out_size, void* d_ws, size_t ws_size,
                              hipStream_t stream) {
    const float* x      = (const float*)d_in[0];
    const int*   tern   = (const int*)d_in[1];
    const float* scales = (const float*)d_in[2];

    signed char* xq = (signed char*)d_ws;                          // 33.6 MB
    signed char* wq = xq + (size_t)TOKENS * IN_F;                  // 16.8 MB
    float*       dx = (float*)(wq + (size_t)OUT_F * IN_F);         // 32 KB
    float*       dw = dx + TOKENS;                                 // 16 KB

    quant_x_kernel<<<TOKENS, 256, 0, stream>>>(x, xq, dx);
    quant_w_kernel<<<OUT_F, 256, 0, stream>>>(tern, scales, wq, dw);

    dim3 grid((TOKENS / BM) * (OUT_F / BN));   // 512
    gemm_i8_kernel<<<grid, 512, 0, stream>>>(xq, wq, dx, dw, (float*)d_out);
}